// Round 7
// baseline (150.192 us; speedup 1.0000x reference)
//
#include <hip/hip_runtime.h>
#include <stdint.h>

#define C_CH 192
#define HW   4096
#define NB   16
#define NO   5
#define ARR_SHORTS 12582912   // shorts per tiled array (NB*C_CH*HW)

typedef __attribute__((ext_vector_type(8)))  short short8;
typedef __attribute__((ext_vector_type(16))) float floatx16;

__device__ __forceinline__ unsigned short f2bf(float f) {
    unsigned int u = __float_as_uint(f);
    unsigned int r = (u + 0x7fffu + ((u >> 16) & 1u)) >> 16;  // RNE to bf16
    return (unsigned short)r;
}

// ---------------- Kernel 1: fp32 -> bf16, THREE fragment-tiled arrays ------------
// X  [w] = x[w]           (center)
// XM [w] = x[max(w-1,0)]  (dx=-1, left-clamped)   -- replaces gemm-side shift_m
// XP [w] = x[min(w+1,63)] (dx=+1, right-clamped)  -- replaces gemm-side shift_p
// Tiled short8 index: grp*16384 + q*32 + c'   (grp = b*6+cb, q = h*8+j8, c' = ch&31)
__global__ __launch_bounds__(256) void convert_kernel(const float* __restrict__ x,
                                                      unsigned short* __restrict__ xb,
                                                      float* __restrict__ norms) {
    if (blockIdx.x == 0 && threadIdx.x < NB * NO) norms[threadIdx.x] = 0.0f;
    int t   = blockIdx.x * 256 + threadIdx.x;   // 1,572,864 threads
    int grp = t >> 14;                          // 96 groups of (b, cb)
    int idx = t & 16383;
    int qhi = idx >> 8;
    int cp  = (idx >> 3) & 31;
    int qlo = idx & 7;
    int q   = qhi * 8 + qlo;
    int b   = grp / 6;
    int cb  = grp - b * 6;
    int ch  = cb * 32 + cp;
    int h   = q >> 3;                           // spatial row 0..63
    int j8  = q & 7;                            // octet within row
    int w8  = j8 * 8;

    const float* row = x + (size_t)(b * C_CH + ch) * HW + h * 64;
    const float4* p = (const float4*)(row + w8);
    float4 v0 = p[0], v1 = p[1];
    float prevf = row[j8 ? w8 - 1 : 0];         // x[w8-1] clamped
    float nextf = row[j8 < 7 ? w8 + 8 : 63];    // x[w8+8] clamped

    unsigned short b0 = f2bf(v0.x), b1 = f2bf(v0.y), b2 = f2bf(v0.z), b3 = f2bf(v0.w);
    unsigned short b4 = f2bf(v1.x), b5 = f2bf(v1.y), b6 = f2bf(v1.z), b7 = f2bf(v1.w);
    unsigned short pv = f2bf(prevf), nx = f2bf(nextf);

    size_t o8 = (size_t)grp * 16384 + q * 32 + cp;    // short8 index
    ushort4* dX = (ushort4*)xb + o8 * 2;
    ushort4* dM = (ushort4*)(xb + ARR_SHORTS) + o8 * 2;
    ushort4* dP = (ushort4*)(xb + 2 * ARR_SHORTS) + o8 * 2;
    ushort4 u;
    u.x = b0; u.y = b1; u.z = b2; u.w = b3; dX[0] = u;
    u.x = b4; u.y = b5; u.z = b6; u.w = b7; dX[1] = u;
    u.x = pv; u.y = b0; u.z = b1; u.w = b2; dM[0] = u;
    u.x = b3; u.y = b4; u.z = b5; u.w = b6; dM[1] = u;
    u.x = b1; u.y = b2; u.z = b3; u.w = b4; dP[0] = u;
    u.x = b5; u.y = b6; u.z = b7; u.w = nx; dP[1] = u;
}

// ---------------- Kernel 2: fused 5-offset Gram — pure load->MFMA loop ----------
// grid 576 = 16 b x 36 (32x32)-tiles; 256 thr = 4 waves; wave wv owns h-rows
// [16wv, 16wv+16) (full K in one block, no partials). Loop s OUTER, g INNER:
// fragment-granular rotation (a:4 frags, b:3 frags x3 arrays = 52 staging VGPRs).
// Per inner iter: 4 x 16B loads + 5 MFMAs, no shuffles, no funnel shifts.
// dy=-1 terms re-indexed: sum_g A[g+1]*B[g] (g=0..62) + A[0]*B[0] boundary (wv 0).
__global__ __launch_bounds__(256) void cofe_gemm(const unsigned short* __restrict__ xb,
                                                 float* __restrict__ out,
                                                 float* __restrict__ norms) {
    int blk  = blockIdx.x;
    int work = (blk & 7) * 72 + (blk >> 3);     // XCD swizzle: 2 batches per XCD
    int b = work / 36;
    int t = work % 36;
    int cbA = t / 6, cbB = t % 6;
    int c0 = cbA * 32, d0 = cbB * 32;

    int wv   = threadIdx.x >> 6;                // 0..3
    int lane = threadIdx.x & 63;
    int lr   = lane & 31;
    int lo   = lane >> 5;
    int laneoff = lo * 32 + lr;                 // short8 units

    const short8* XA = (const short8*)xb + (size_t)(b * 6 + cbA) * 16384;
    const short8* XB = (const short8*)xb + (size_t)(b * 6 + cbB) * 16384;
    const short8* MB = (const short8*)(xb + ARR_SHORTS) + (size_t)(b * 6 + cbB) * 16384;
    const short8* PB = (const short8*)(xb + 2 * ARR_SHORTS) + (size_t)(b * 6 + cbB) * 16384;

    floatx16 acc[5];
    #pragma unroll
    for (int o = 0; o < 5; ++o)
        #pragma unroll
        for (int e = 0; e < 16; ++e)
            acc[o][e] = 0.0f;

    int h0 = wv * 16;
#define FR(row, s) (((row) * 8 + 2 * (s)) * 32 + laneoff)

    #pragma unroll
    for (int s = 0; s < 4; ++s) {
        short8 a[4], bx[3], bm[3], bp[3];
        // pipeline init: a rows h0..h0+2, b rows h0..h0+1
        a[0]  = XA[FR(h0, s)];
        a[1]  = XA[FR(h0 + 1, s)];
        a[2]  = XA[FR(h0 + 2, s)];
        bx[0] = XB[FR(h0, s)];  bm[0] = MB[FR(h0, s)];  bp[0] = PB[FR(h0, s)];
        bx[1] = XB[FR(h0 + 1, s)]; bm[1] = MB[FR(h0 + 1, s)]; bp[1] = PB[FR(h0 + 1, s)];

        // h = 0 boundary: dy=-1 offsets pair center row 0 with clamped side row 0
        if (wv == 0) {
            acc[0] = __builtin_amdgcn_mfma_f32_32x32x16_bf16(a[0], bm[0], acc[0], 0, 0, 0);
            acc[1] = __builtin_amdgcn_mfma_f32_32x32x16_bf16(a[0], bx[0], acc[1], 0, 0, 0);
            acc[2] = __builtin_amdgcn_mfma_f32_32x32x16_bf16(a[0], bp[0], acc[2], 0, 0, 0);
        }

        #pragma unroll
        for (int r = 0; r < 16; ++r) {
            int g   = h0 + r;
            const int ia  = r & 3;              // slot of row g
            const int ia1 = (r + 1) & 3;        // slot of row g+1
            const int ipa = (r + 3) & 3;        // prefetch slot <- row g+3
            const int ib  = r % 3;              // slot of row g
            const int ipb = (r + 2) % 3;        // prefetch slot <- row g+2
            int ga = (g + 3 < 64) ? g + 3 : 63;
            int gb = (g + 2 < 64) ? g + 2 : 63;

            a[ipa]  = XA[FR(ga, s)];
            bx[ipb] = XB[FR(gb, s)];
            bm[ipb] = MB[FR(gb, s)];
            bp[ipb] = PB[FR(gb, s)];

            // OFFSETS: 0:(-1,-1) 1:(-1,0) 2:(-1,1) 3:(0,-1) 4:(0,0)
            acc[4] = __builtin_amdgcn_mfma_f32_32x32x16_bf16(a[ia],  bx[ib], acc[4], 0, 0, 0);
            acc[3] = __builtin_amdgcn_mfma_f32_32x32x16_bf16(a[ia],  bm[ib], acc[3], 0, 0, 0);
            if (r < 15 || wv < 3) {             // dy=-1 sum runs g = 0..62
                acc[1] = __builtin_amdgcn_mfma_f32_32x32x16_bf16(a[ia1], bx[ib], acc[1], 0, 0, 0);
                acc[0] = __builtin_amdgcn_mfma_f32_32x32x16_bf16(a[ia1], bm[ib], acc[0], 0, 0, 0);
                acc[2] = __builtin_amdgcn_mfma_f32_32x32x16_bf16(a[ia1], bp[ib], acc[2], 0, 0, 0);
            }
        }
    }
#undef FR

    // ---- epilogue: LDS-reduce 4 wave partials, store out, 1 atomic per offset ----
    __shared__ float red[4096];   // 16 KB
    __shared__ float wsum[4];
    float4* red4 = (float4*)red;
    size_t obase = (size_t)b * NO * (C_CH * C_CH);
    int tt = threadIdx.x;

    for (int o = 0; o < 5; ++o) {
        __syncthreads();
        #pragma unroll
        for (int reg = 0; reg < 16; ++reg) {
            int row = (reg & 3) + 8 * (reg >> 2) + 4 * lo;  // C/D layout (m74/m101)
            red[wv * 1024 + row * 32 + lr] = acc[o][reg];
        }
        __syncthreads();
        float4 s  = red4[tt];
        float4 s1 = red4[256 + tt];
        float4 s2 = red4[512 + tt];
        float4 s3 = red4[768 + tt];
        s.x += s1.x + s2.x + s3.x;
        s.y += s1.y + s2.y + s3.y;
        s.z += s1.z + s2.z + s3.z;
        s.w += s1.w + s2.w + s3.w;
        int row = tt >> 3;
        int col = (tt & 7) * 4;
        float* op = out + obase + (size_t)o * (C_CH * C_CH)
                  + (size_t)(c0 + row) * C_CH + d0 + col;
        *(float4*)op = s;

        float ss = s.x * s.x + s.y * s.y + s.z * s.z + s.w * s.w;
        #pragma unroll
        for (int off = 32; off; off >>= 1) ss += __shfl_down(ss, off, 64);
        if (lane == 0) wsum[wv] = ss;
        __syncthreads();
        if (tt == 0) atomicAdd(&norms[b * NO + o], wsum[0] + wsum[1] + wsum[2] + wsum[3]);
    }
}

// ---------------- Kernel 3: scale by 1/norm ----------------
__global__ __launch_bounds__(256) void scale_kernel(float* __restrict__ out,
                                                    const float* __restrict__ norms) {
    int g  = blockIdx.x * 256 + threadIdx.x;    // float4 index, 737,280 total
    int bo = blockIdx.x / 36;                   // 9216 float4 per (b,o)
    float s = norms[bo];
    float inv = 1.0f / fmaxf(sqrtf(s), 1e-12f);
    float4 v = ((const float4*)out)[g];
    v.x *= inv; v.y *= inv; v.z *= inv; v.w *= inv;
    ((float4*)out)[g] = v;
}

extern "C" void kernel_launch(void* const* d_in, const int* in_sizes, int n_in,
                              void* d_out, int out_size, void* d_ws, size_t ws_size,
                              hipStream_t stream) {
    const float* x = (const float*)d_in[0];
    float* out = (float*)d_out;
    float* norms = (float*)d_ws;                                   // 80 floats (+pad)
    unsigned short* xb = (unsigned short*)((char*)d_ws + 512);     // 3 x 25,165,824 B tiled

    convert_kernel<<<6144, 256, 0, stream>>>(x, xb, norms);
    cofe_gemm<<<576, 256, 0, stream>>>(xb, out, norms);
    scale_kernel<<<2880, 256, 0, stream>>>(out, norms);
}